// Round 7
// baseline (144.953 us; speedup 1.0000x reference)
//
#include <hip/hip_runtime.h>
#include <math.h>

// Problem constants (from reference setup_inputs)
static constexpr int N_ = 4, R_ = 256, C_ = 1024, H_ = 50, W_ = 50, P_ = 7;
static constexpr int HW_ = H_ * W_;
static constexpr int PP_ = P_ * P_;          // 49 output pixels per (roi, channel)
static constexpr int CH_ = 64;               // channels per wave; 16 waves per roi

typedef const __attribute__((address_space(1))) void* gaddr_t;
typedef __attribute__((address_space(3))) void* laddr_t;

__device__ __forceinline__ void ld_lds4(const float* g, float* l) {
    // async global->LDS, 4B per lane, dest = wave-uniform base + lane*4
    __builtin_amdgcn_global_load_lds((gaddr_t)g, (laddr_t)l, 4, 0, 0);
}

// Counted waits (T4). One STAGE2 = 8 loads. vmcnt(8): all but the 8 newest
// VMEM ops drained -> the older STAGE2 (and all older stores) has landed.
#define VMWAIT8()  asm volatile("s_waitcnt vmcnt(8)" ::: "memory")
#define LGKMWAIT() asm volatile("s_waitcnt lgkmcnt(0)" ::: "memory")

// --- XOR-swizzled, channel-pair-interleaved patch ------------------------
// Patch position p (16x16 window): q = dy>>1, t = (dy&1)<<4 | dx,
// p_swz = (q<<5) | (t ^ swz5(q)).  LDS word w = 2*p_swz + ch (ch in {0,1}).
// One ds_read_b64 at float2-index p_swz returns BOTH channels' value at that
// patch position -> DS instructions per channel halve (9 b32 -> 4.5 b64).
// Bank-pair spread: (11q)&15 = {0,11,6,1,12,7,2,13} all distinct -> the
// stride-16 lane-lattice resonance stays broken under b64 addressing.
// Same mapping is used on staging SOURCE coords and reader ADDRESSES.
__device__ __forceinline__ int swz5(int q) { return (q * 11) & 31; }

__device__ __forceinline__ int patch_addr(int dy, int dx) {   // -> float2 index
    const int q = dy >> 1;
    const int t = ((dy & 1) << 4) | dx;
    return (q << 5) | (t ^ swz5(q));
}

// Window-relative per-axis geometry for the two sub-samples of one pooled cell.
// Sample spacing < 1 px => both samples' corners lie in a 3-wide window at
// rel0 = floor(p0) - base. Zero-padding validity folded into weights.
__device__ __forceinline__ void axis_rel(float p0, float p1, int base, int L,
                                         int& rel0, float wA[3], float wB[3]) {
    float f0 = floorf(p0); int i0 = (int)f0; float a0 = p0 - f0;
    float f1 = floorf(p1); int i1 = (int)f1; float a1 = p1 - f1;
    const bool o = (i1 > i0);
    wA[0] = 1.0f - a0; wA[1] = a0; wA[2] = 0.0f;
    wB[0] = o ? 0.0f : (1.0f - a1);
    wB[1] = o ? (1.0f - a1) : a1;
    wB[2] = o ? a1 : 0.0f;
#pragma unroll
    for (int j = 0; j < 3; ++j) {
        int ij = i0 + j;
        if (ij < 0 || ij > L - 1) { wA[j] = 0.0f; wB[j] = 0.0f; }
    }
    rel0 = min(max(i0 - base, 0), 13);   // window-relative; dy,dx stay in [0,15]
}

// Gather 9 float2 (two channels at once) and reduce each channel.
__device__ __forceinline__ void gather9x2(const float* __restrict__ cur,
                                          const int a[9],
                                          const float wyA[3], const float wyB[3],
                                          const float wxA[3], const float wxB[3],
                                          float& rX, float& rY) {
    const float2* __restrict__ cp = reinterpret_cast<const float2*>(cur);
    float2 v[9];
#pragma unroll
    for (int i = 0; i < 9; ++i) v[i] = cp[a[i]];

#pragma unroll
    for (int ch = 0; ch < 2; ++ch) {
        const float v00 = ch ? v[0].y : v[0].x, v01 = ch ? v[1].y : v[1].x, v02 = ch ? v[2].y : v[2].x;
        const float v10 = ch ? v[3].y : v[3].x, v11 = ch ? v[4].y : v[4].x, v12 = ch ? v[5].y : v[5].x;
        const float v20 = ch ? v[6].y : v[6].x, v21 = ch ? v[7].y : v[7].x, v22 = ch ? v[8].y : v[8].x;

        const float tA0 = fmaf(wyA[2], v20, fmaf(wyA[1], v10, wyA[0] * v00));
        const float tA1 = fmaf(wyA[2], v21, fmaf(wyA[1], v11, wyA[0] * v01));
        const float tA2 = fmaf(wyA[2], v22, fmaf(wyA[1], v12, wyA[0] * v02));
        const float tB0 = fmaf(wyB[2], v20, fmaf(wyB[1], v10, wyB[0] * v00));
        const float tB1 = fmaf(wyB[2], v21, fmaf(wyB[1], v11, wyB[0] * v01));
        const float tB2 = fmaf(wyB[2], v22, fmaf(wyB[1], v12, wyB[0] * v02));

        const float s00 = fmaf(wxA[2], tA2, fmaf(wxA[1], tA1, wxA[0] * tA0));
        const float s01 = fmaf(wxB[2], tA2, fmaf(wxB[1], tA1, wxB[0] * tA0));
        const float s10 = fmaf(wxA[2], tB2, fmaf(wxA[1], tB1, wxA[0] * tB0));
        const float s11 = fmaf(wxB[2], tB2, fmaf(wxB[1], tB1, wxB[0] * tB0));

        const float best = fmaxf(fmaxf(s00, s01), fmaxf(s10, s11));
        if (ch) rY = best; else rX = best;
    }
}

// Block = 4 waves. Grid = N*R*4. Block (nr, q); wave w -> channels (q*4+w)*64..+63.
// Lane = output pixel (49 active / 64). Per-wave double-buffered channel-PAIR
// patches; single-wave producer==consumer => counted vmcnt/lgkmcnt, no barriers.
__global__ __launch_bounds__(256) void roipool_kernel(
    const float* __restrict__ rois,
    const float* __restrict__ fm,
    float* __restrict__ out) {

    __shared__ float patch[4][2][512];   // [wave][buf][2ch-interleaved 16x16], 16 KB

    const int b  = blockIdx.x;
    const int q  = b & 3;
    const int nr = b >> 2;               // n*R + r
    const int n  = nr >> 8;              // R_ = 256
    const int lane = threadIdx.x & 63;
    const int wv = __builtin_amdgcn_readfirstlane(threadIdx.x >> 6);
    const int c0 = (q * 4 + wv) * CH_;

    // roi: (y, x, h, w) image coords; stride 16
    const float4 roi = reinterpret_cast<const float4*>(rois)[nr];
    const float y1 = roi.x * 0.0625f;
    const float x1 = roi.y * 0.0625f;
    const float y2 = (roi.x + roi.z) * 0.0625f;
    const float x2 = (roi.y + roi.w) * 0.0625f;
    const float sy = (y2 - y1) * (1.0f / 13.0f);
    const float sx = (x2 - x1) * (1.0f / 13.0f);

    const int y0 = max((int)floorf(y1), 0);   // window origin
    const int x0 = max((int)floorf(x1), 0);

    // Staging source offsets: LDS word w = t*64+lane -> ch = w&1,
    // swizzled patch pos pw = w>>1, unswizzled (dy,dx); clamped in-plane
    // (clamped cells carry zero weight). ch*HW_ folded into the offset.
    int soff[8];
#pragma unroll
    for (int t = 0; t < 8; ++t) {
        const int w  = t * 64 + lane;
        const int ch = w & 1;
        const int pw = w >> 1;
        const int qq = pw >> 5;
        const int lo = (pw & 31) ^ swz5(qq);
        const int dy = (qq << 1) | (lo >> 4);
        const int dx = lo & 15;
        soff[t] = ch * HW_ + min(y0 + dy, H_ - 1) * W_ + min(x0 + dx, W_ - 1);
    }

    int pi = lane / 7;
    int pj = lane - pi * 7;
    const bool active = lane < PP_;
    if (!active) { pi = 0; pj = 0; }     // idle lanes mirror lane 0 -> broadcast

    const float py0 = y1 + sy * (float)(2 * pi);
    const float py1 = y1 + sy * (float)(2 * pi + 1);
    const float px0 = x1 + sx * (float)(2 * pj);
    const float px1 = x1 + sx * (float)(2 * pj + 1);

    int ryr; float wyA[3], wyB[3];
    axis_rel(py0, py1, y0, H_, ryr, wyA, wyB);
    int cxr; float wxA[3], wxB[3];
    axis_rel(px0, px1, x0, W_, cxr, wxA, wxB);

    // 9 swizzled float2 gather indices (per-lane, loop-invariant registers)
    int a[9];
#pragma unroll
    for (int r = 0; r < 3; ++r)
#pragma unroll
        for (int c = 0; c < 3; ++c)
            a[r * 3 + c] = patch_addr(ryr + r, cxr + c);

    const float* __restrict__ pbase = fm + (size_t)(n * C_ + c0) * HW_;
    float* __restrict__ po = out + ((size_t)nr * C_ + c0) * PP_ + lane;

    float* const b0 = &patch[wv][0][0];
    float* const b1 = &patch[wv][1][0];

#define STAGE2(BUF, PL) do { \
        ld_lds4((PL) + soff[0], (BUF));       \
        ld_lds4((PL) + soff[1], (BUF) + 64);  \
        ld_lds4((PL) + soff[2], (BUF) + 128); \
        ld_lds4((PL) + soff[3], (BUF) + 192); \
        ld_lds4((PL) + soff[4], (BUF) + 256); \
        ld_lds4((PL) + soff[5], (BUF) + 320); \
        ld_lds4((PL) + soff[6], (BUF) + 384); \
        ld_lds4((PL) + soff[7], (BUF) + 448); \
    } while (0)

    // 2 buffers x 2 channels in flight. Tail STAGEs clamp to the last even
    // pair (dummy restage) so every body issues exactly 8 loads -> uniform vmcnt.
    STAGE2(b0, pbase);                        // ch 0,1
    STAGE2(b1, pbase + 2 * HW_);              // ch 2,3

    for (int k = 0; k < CH_; k += 4) {
        float r0, r1, r2, r3;
        VMWAIT8();                            // b0 pair (k, k+1) landed
        gather9x2(b0, a, wyA, wyB, wxA, wxB, r0, r1);
        if (active) {
            po[k * PP_]       = r0;
            po[(k + 1) * PP_] = r1;
        }
        LGKMWAIT();                           // ds_reads done -> safe to overwrite
        STAGE2(b0, pbase + (size_t)min(k + 4, CH_ - 2) * HW_);

        VMWAIT8();                            // b1 pair (k+2, k+3) landed
        gather9x2(b1, a, wyA, wyB, wxA, wxB, r2, r3);
        if (active) {
            po[(k + 2) * PP_] = r2;
            po[(k + 3) * PP_] = r3;
        }
        LGKMWAIT();
        STAGE2(b1, pbase + (size_t)min(k + 6, CH_ - 2) * HW_);
    }
#undef STAGE2
}

extern "C" void kernel_launch(void* const* d_in, const int* in_sizes, int n_in,
                              void* d_out, int out_size, void* d_ws, size_t ws_size,
                              hipStream_t stream) {
    const float* rois = (const float*)d_in[0];        // [4,256,4]
    const float* fm   = (const float*)d_in[1];        // [4,1024,50,50]
    float* out        = (float*)d_out;                // [4,256,1024,7,7]

    const int blocks = N_ * R_ * 4;                   // 4096
    roipool_kernel<<<blocks, 256, 0, stream>>>(rois, fm, out);
}

// Round 8
// 125.310 us; speedup vs baseline: 1.1568x; 1.1568x over previous
//
#include <hip/hip_runtime.h>
#include <math.h>

// Problem constants (from reference setup_inputs)
static constexpr int N_ = 4, R_ = 256, C_ = 1024, H_ = 50, W_ = 50, P_ = 7;
static constexpr int HW_ = H_ * W_;
static constexpr int PP_ = P_ * P_;            // 49 output pixels per (roi, channel)
static constexpr int CH_ = 64;                 // channels per wave; 16 waves per roi
static constexpr int FM_WORDS = N_ * C_ * HW_; // 10,240,000

typedef const __attribute__((address_space(1))) void* gaddr_t;
typedef __attribute__((address_space(3))) void* laddr_t;

__device__ __forceinline__ void ld_lds16(const float* g, float* l) {
    // async global->LDS DMA, 16B per lane: ONE instruction stages the whole
    // 1KB patch (64 lanes x 16B). Dest is linear (base + lane*16).
    __builtin_amdgcn_global_load_lds((gaddr_t)g, (laddr_t)l, 16, 0, 0);
}

// Counted waits (T4). 1 stage instr + 1 store per channel. vmcnt(3): allows
// the 3 newest VMEM ops outstanding -> the stage 4 channels back has landed.
// Correct whether or not stores count toward vmcnt (stores are interleaved
// newer ops; allowing 3 newest can only over-drain, never under-drain).
#define VMWAIT3()  asm volatile("s_waitcnt vmcnt(3)" ::: "memory")
#define LGKMWAIT() asm volatile("s_waitcnt lgkmcnt(0)" ::: "memory")

// --- chunk-swizzled 16x16 patch -------------------------------------------
// LDS chunk l (16B = 4 words) holds patch row = l>>2, quarter q = (l&3)^(row&3).
// Source chunks stay 16B-contiguous in global (DMA-compatible); the XOR on the
// quarter spreads a fixed column dx across 8 banks over the 16 rows, breaking
// the stride-16 vertical bank resonance. Same mapping on stage & read sides.
__device__ __forceinline__ int paddr(int dy, int dx) {      // -> word index
    const int ch = (dy << 2) | (((dx >> 2) ^ dy) & 3);
    return (ch << 2) | (dx & 3);
}

// Window-relative per-axis geometry for the two sub-samples of one pooled cell.
// Sample spacing < 1 px => both samples' corners lie in a 3-wide window at
// rel0 = floor(p0) - base. Zero-padding validity folded into weights.
__device__ __forceinline__ void axis_rel(float p0, float p1, int base, int L,
                                         int& rel0, float wA[3], float wB[3]) {
    float f0 = floorf(p0); int i0 = (int)f0; float a0 = p0 - f0;
    float f1 = floorf(p1); int i1 = (int)f1; float a1 = p1 - f1;
    const bool o = (i1 > i0);
    wA[0] = 1.0f - a0; wA[1] = a0; wA[2] = 0.0f;
    wB[0] = o ? 0.0f : (1.0f - a1);
    wB[1] = o ? (1.0f - a1) : a1;
    wB[2] = o ? a1 : 0.0f;
#pragma unroll
    for (int j = 0; j < 3; ++j) {
        int ij = i0 + j;
        if (ij < 0 || ij > L - 1) { wA[j] = 0.0f; wB[j] = 0.0f; }
    }
    rel0 = min(max(i0 - base, 0), 13);   // window-relative; dy,dx stay in [0,15]
}

__device__ __forceinline__ float gather9(const float* __restrict__ cur,
                                         const int a[9],
                                         const float wyA[3], const float wyB[3],
                                         const float wxA[3], const float wxB[3]) {
    const float v00 = cur[a[0]], v01 = cur[a[1]], v02 = cur[a[2]];
    const float v10 = cur[a[3]], v11 = cur[a[4]], v12 = cur[a[5]];
    const float v20 = cur[a[6]], v21 = cur[a[7]], v22 = cur[a[8]];

    const float tA0 = fmaf(wyA[2], v20, fmaf(wyA[1], v10, wyA[0] * v00));
    const float tA1 = fmaf(wyA[2], v21, fmaf(wyA[1], v11, wyA[0] * v01));
    const float tA2 = fmaf(wyA[2], v22, fmaf(wyA[1], v12, wyA[0] * v02));
    const float tB0 = fmaf(wyB[2], v20, fmaf(wyB[1], v10, wyB[0] * v00));
    const float tB1 = fmaf(wyB[2], v21, fmaf(wyB[1], v11, wyB[0] * v01));
    const float tB2 = fmaf(wyB[2], v22, fmaf(wyB[1], v12, wyB[0] * v02));

    const float s00 = fmaf(wxA[2], tA2, fmaf(wxA[1], tA1, wxA[0] * tA0));
    const float s01 = fmaf(wxB[2], tA2, fmaf(wxB[1], tA1, wxB[0] * tA0));
    const float s10 = fmaf(wxA[2], tB2, fmaf(wxA[1], tB1, wxA[0] * tB0));
    const float s11 = fmaf(wxB[2], tB2, fmaf(wxB[1], tB1, wxB[0] * tB0));

    return fmaxf(fmaxf(s00, s01), fmaxf(s10, s11));
}

// Block = 4 waves. Grid = N*R*4. Block (nr, q); wave w -> channels (q*4+w)*64..+63.
// Lane = output pixel (49 active / 64). Per-wave 4-deep LDS ring; single-wave
// producer==consumer => counted vmcnt/lgkmcnt, no barriers.
__global__ __launch_bounds__(256) void roipool_kernel(
    const float* __restrict__ rois,
    const float* __restrict__ fm,
    float* __restrict__ out) {

    __shared__ float patch[4][4][256];   // [wave][ring][16x16 patch], 16 KB

    const int b  = blockIdx.x;
    const int q  = b & 3;
    const int nr = b >> 2;               // n*R + r
    const int n  = nr >> 8;              // R_ = 256
    const int lane = threadIdx.x & 63;
    const int wv = __builtin_amdgcn_readfirstlane(threadIdx.x >> 6);
    const int c0 = (q * 4 + wv) * CH_;

    // roi: (y, x, h, w) image coords; stride 16
    const float4 roi = reinterpret_cast<const float4*>(rois)[nr];
    const float y1 = roi.x * 0.0625f;
    const float x1 = roi.y * 0.0625f;
    const float y2 = (roi.x + roi.z) * 0.0625f;
    const float x2 = (roi.y + roi.w) * 0.0625f;
    const float sy = (y2 - y1) * (1.0f / 13.0f);
    const float sx = (x2 - x1) * (1.0f / 13.0f);

    const int y0 = max((int)floorf(y1), 0);   // window origin
    const int x0 = max((int)floorf(x1), 0);

    // Staging source: lane l supplies chunk l = patch row l>>2, quarter
    // (l&3)^(row&3). Off-window cells (x>49 wraps into next row, y>49 into the
    // next plane) all carry zero weight; only the buffer end needs a clamp.
    const int srow = lane >> 2;
    const int sq   = (lane & 3) ^ (srow & 3);
    const int soff = (y0 + srow) * W_ + x0 + 4 * sq;   // word offset in plane

    int pi = lane / 7;
    int pj = lane - pi * 7;
    const bool active = lane < PP_;
    if (!active) { pi = 0; pj = 0; }     // idle lanes mirror lane 0 -> broadcast

    const float py0 = y1 + sy * (float)(2 * pi);
    const float py1 = y1 + sy * (float)(2 * pi + 1);
    const float px0 = x1 + sx * (float)(2 * pj);
    const float px1 = x1 + sx * (float)(2 * pj + 1);

    int ryr; float wyA[3], wyB[3];
    axis_rel(py0, py1, y0, H_, ryr, wyA, wyB);
    int cxr; float wxA[3], wxB[3];
    axis_rel(px0, px1, x0, W_, cxr, wxA, wxB);

    // 9 swizzled gather word-indices (per-lane, loop-invariant registers)
    int a[9];
#pragma unroll
    for (int r = 0; r < 3; ++r)
#pragma unroll
        for (int c = 0; c < 3; ++c)
            a[r * 3 + c] = paddr(ryr + r, cxr + c);

    const int pw0 = (n * C_ + c0) * HW_;      // absolute word offset of ch c0
    float* __restrict__ po = out + ((size_t)nr * C_ + c0) * PP_ + lane;

    float* const s0 = &patch[wv][0][0];
    float* const s1 = &patch[wv][1][0];
    float* const s2 = &patch[wv][2][0];
    float* const s3 = &patch[wv][3][0];

    // ONE width-16 DMA stages a whole channel patch; clamp vs buffer end.
#define STAGE(BUF, KK) do { \
        const int w_ = min(pw0 + (KK) * HW_ + soff, FM_WORDS - 4); \
        ld_lds16(fm + w_, (BUF)); \
    } while (0)

    STAGE(s0, 0);
    STAGE(s1, 1);
    STAGE(s2, 2);
    STAGE(s3, 3);

    for (int k = 0; k < CH_; k += 4) {
        VMWAIT3();
        const float r0 = gather9(s0, a, wyA, wyB, wxA, wxB);
        if (active) po[k * PP_] = r0;
        LGKMWAIT();
        STAGE(s0, min(k + 4, CH_ - 1));      // tail: dummy restage, uniform vmcnt

        VMWAIT3();
        const float r1 = gather9(s1, a, wyA, wyB, wxA, wxB);
        if (active) po[(k + 1) * PP_] = r1;
        LGKMWAIT();
        STAGE(s1, min(k + 5, CH_ - 1));

        VMWAIT3();
        const float r2 = gather9(s2, a, wyA, wyB, wxA, wxB);
        if (active) po[(k + 2) * PP_] = r2;
        LGKMWAIT();
        STAGE(s2, min(k + 6, CH_ - 1));

        VMWAIT3();
        const float r3 = gather9(s3, a, wyA, wyB, wxA, wxB);
        if (active) po[(k + 3) * PP_] = r3;
        LGKMWAIT();
        STAGE(s3, min(k + 7, CH_ - 1));
    }
#undef STAGE
}

extern "C" void kernel_launch(void* const* d_in, const int* in_sizes, int n_in,
                              void* d_out, int out_size, void* d_ws, size_t ws_size,
                              hipStream_t stream) {
    const float* rois = (const float*)d_in[0];        // [4,256,4]
    const float* fm   = (const float*)d_in[1];        // [4,1024,50,50]
    float* out        = (float*)d_out;                // [4,256,1024,7,7]

    const int blocks = N_ * R_ * 4;                   // 4096
    roipool_kernel<<<blocks, 256, 0, stream>>>(rois, fm, out);
}